// Round 20
// baseline (550.012 us; speedup 1.0000x reference)
//
#include <hip/hip_runtime.h>
#include <math.h>

#pragma clang fp contract(fast)

#define S    612
#define TT   8192
#define NB   32
#define SPW  256          // per-wave emission row width in floats (4 per lane)

typedef float v2f __attribute__((ext_vector_type(2)));

// workspace layout (bytes)
#define WIN_OFF   0        // 640 float4 = 10240
#define IV_OFF    10240    // 4 floats
#define EMIS_OFF  16384    // 4*100*256 floats = 409600 -> ends 425984
#define OBS_OFF   425984   // 32*8192 ints = 1 MB

// incoming-weight table: wIn2[t] = (in0,in1,in2,in3), in_k = row((t-k)%S)[k]
__global__ __launch_bounds__(256) void prep_tables(
    const float* __restrict__ tk, const float* __restrict__ ik,
    float* __restrict__ wIn2, float* __restrict__ Ivec)
{
    int i = blockIdx.x * 256 + threadIdx.x;
    if (i < S) {
        float l0 = tk[3*i], l1 = tk[3*i+1], l2 = tk[3*i+2], l3 = 1.0f;
        float m = fmaxf(fmaxf(l0, l1), fmaxf(l2, l3));
        float e0 = expf(l0-m), e1 = expf(l1-m), e2 = expf(l2-m), e3 = expf(l3-m);
        float inv = 1.0f / (e0+e1+e2+e3);
        wIn2[4*i + 0]              = e0*inv;
        wIn2[4*((i+1)%S) + 1]      = e1*inv;
        wIn2[4*((i+2)%S) + 2]      = e2*inv;
        wIn2[4*((i+3)%S) + 3]      = e3*inv;
    } else if (i < 640) {
        wIn2[4*i+0] = 0.f; wIn2[4*i+1] = 0.f; wIn2[4*i+2] = 0.f; wIn2[4*i+3] = 0.f;
    } else if (i == 640) {
        float l0 = ik[0], l1 = ik[1], l2 = ik[2], l3 = ik[3];
        float m = fmaxf(fmaxf(l0,l1), fmaxf(l2,l3));
        float e0 = expf(l0-m), e1 = expf(l1-m), e2 = expf(l2-m), e3 = expf(l3-m);
        float inv = 1.0f / (e0+e1+e2+e3);
        Ivec[0]=e0*inv; Ivec[1]=e1*inv; Ivec[2]=e2*inv; Ivec[3]=e3*inv;
    }
}

// per-wave emission tables; wave wv, row o, lane ln holds float4
// (E(pos0),E(pos2),E(pos1),E(pos3)) for local pos 4*ln+c,
// state s = (haloBase_wv + pos) % 612; zero for pads / state 611.
// halo = 96 positions; owned = 152 (wv 0..2) / 156 (wv 3).
__global__ __launch_bounds__(256) void prep_emis4(
    const float* __restrict__ ek, float* __restrict__ emisP)
{
    int tid = blockIdx.x * 256 + threadIdx.x;
    if (tid >= 4*100*SPW) return;
    int wv = tid / (100*SPW);
    int r  = tid % (100*SPW);
    int o  = r / SPW;
    int q  = r % SPW;
    int ln = q >> 2, j = q & 3;
    int c = (j==0) ? 0 : (j==1) ? 2 : (j==2) ? 1 : 3;
    int pos = 4*ln + c;
    int haloBase = (wv==0) ? 516 : (wv==1) ? 56 : (wv==2) ? 208 : 360;
    int CWv = (wv==3) ? 252 : 248;
    float val = 0.0f;
    if (pos < CWv) {
        int s = (haloBase + pos) % S;
        if (s < S-1) {
            int ctx = o >> 2, le = o & 3;
            if (ctx == 0) {
                val = 0.25f;
            } else {
                const float* g = ek + s*96 + (ctx-1)*4;
                float a0=g[0], a1=g[1], a2=g[2], a3=g[3];
                float m = fmaxf(fmaxf(a0,a1), fmaxf(a2,a3));
                float x0=expf(a0-m), x1=expf(a1-m), x2=expf(a2-m), x3=expf(a3-m);
                float inv = 1.0f/(x0+x1+x2+x3);
                val = ((le==0)?x0:(le==1)?x1:(le==2)?x2:x3) * inv;
            }
        }
    }
    emisP[tid] = val;
}

__global__ __launch_bounds__(256) void extract_obs(
    const float* __restrict__ x, int* __restrict__ obs)
{
    int row  = blockIdx.x * 4 + (threadIdx.x >> 6);
    int lane = threadIdx.x & 63;
    if (row >= NB*TT) return;
    const float* r = x + (size_t)row * 101;
    float acc = r[lane] * (float)lane;
    if (lane < 37) acc += r[64 + lane] * (float)(64 + lane);
    #pragma unroll
    for (int m = 32; m >= 1; m >>= 1) acc += __shfl_xor(acc, m, 64);
    if (lane == 0) obs[row] = (int)(acc + 0.5f);
}

__device__ __forceinline__ float dpp_up1(float x) {
    int xi = __builtin_bit_cast(int, x);
    int r = __builtin_amdgcn_update_dpp(0, xi, 0x138, 0xF, 0xF, true);
    return __builtin_bit_cast(float, r);
}
template<int CTRL>
__device__ __forceinline__ float dpp_add(float x) {
    int sh = __builtin_amdgcn_update_dpp(0, __builtin_bit_cast(int, x), CTRL, 0xF, 0xF, true);
    return x + __builtin_bit_cast(float, sh);
}

// 2-pair core, tree-form FMA (chain depth 3): p[0]=(pos0,pos2), p[1]=(pos1,pos3).
// Lane 0's missing predecessors are DPP zeros -> garbage creeps into the
// 96-halo only (3 positions/step, 32 steps); no wrap patch needed.
#define CORE(E0,E1)                                                          \
  {                                                                          \
    float pm1 = dpp_up1(p[1].y);        /* pos 4l-1 */                       \
    float pm2 = dpp_up1(p[0].y);        /* pos 4l-2 */                       \
    float pm3 = dpp_up1(p[1].x);        /* pos 4l-3 */                       \
    v2f B1; B1.x = pm1; B1.y = p[1].x;                                       \
    v2f B2; B2.x = pm2; B2.y = p[0].x;                                       \
    v2f B3; B3.x = pm3; B3.y = pm1;                                          \
    v2f t0 = p[0]*W[0][0];  t0 = B1*W[0][1] + t0;                            \
    v2f u0 = B2*W[0][2];    u0 = B3*W[0][3] + u0;                            \
    v2f c0 = t0 + u0;                                                        \
    v2f t1 = p[1]*W[1][0];  t1 = p[0]*W[1][1] + t1;                          \
    v2f u1 = B1*W[1][2];    u1 = B2*W[1][3] + u1;                            \
    v2f c1 = t1 + u1;                                                        \
    p[0] = c0*(E0); p[1] = c1*(E1);                                          \
  }

#define PFX(JB, OV)                                                          \
  { int _oo = __builtin_amdgcn_readfirstlane(OV);                            \
    float4 _q = *(const float4*)(ebase + _oo*SPW + 4*l);                     \
    eb[JB][0] = (v2f){_q.x,_q.y};                                            \
    eb[JB][1] = (v2f){_q.z,_q.w}; }

#define STEPX(JB, OV)  CORE(eb[JB][0],eb[JB][1]); PFX(JB, OV);
#define STEPC(JB)      CORE(eb[JB][0],eb[JB][1]);

// spread z-reduce: snapshot masked sum, then one DPP stage per step
#define SNAP()  { v2f _t = p[0] + p[1]; zl = (_t.x + _t.y) * zmask; }
#define ZST(C)  zl = dpp_add<C>(zl);

// boundary: zl already fully reduced (spread over steps 27..32).
// Halo+z exchange via LDS, then fold 1/z into the NEXT step's emission
// buffer (eb[1]) instead of scaling p on-chain; logf off-chain into ll.
#define BOUNDARY()                                                           \
  { if (l >= exBase && l < exBase + 24) {                                    \
      float* _o = &box[par][wv][4*(l - exBase)];                             \
      _o[0]=p[0].x; _o[1]=p[1].x; _o[2]=p[0].y; _o[3]=p[1].y;                \
    }                                                                        \
    if (l == 63) box[par][wv][96] = zl;                                      \
    __syncthreads();                                                         \
    if (l < 24) {                                                            \
      const float* _q = &box[par][(wv+3)&3][4*l];                            \
      p[0].x=_q[0]; p[1].x=_q[1]; p[0].y=_q[2]; p[1].y=_q[3];                \
    }                                                                        \
    float z = ((box[par][0][96] + box[par][1][96]) +                         \
               (box[par][2][96] + box[par][3][96]));                         \
    float inv_ = __builtin_amdgcn_rcpf(z);                                   \
    ll += __logf(z);                                                         \
    v2f _iv; _iv.x = inv_; _iv.y = inv_;                                     \
    eb[1][0] = eb[1][0]*_iv; eb[1][1] = eb[1][1]*_iv;                        \
    par ^= 1; }

// 4 waves per block, 1 batch per block; wave wv owns 152/156 states + 96 halo;
// 32-step windows between boundaries.
__global__ __launch_bounds__(256, 1) void forward(
    const float* __restrict__ emisP, const float4* __restrict__ wIn2,
    const float* __restrict__ Ivec, const int* __restrict__ obs,
    float* __restrict__ out)
{
    const int tid = threadIdx.x;
    const int l   = tid & 63;
    const int wv  = tid >> 6;
    const int b   = blockIdx.x;
    const int* obp = obs + b * TT;
    const int haloBase = (wv==0) ? 516 : (wv==1) ? 56 : (wv==2) ? 208 : 360;
    const int owned    = (wv==3) ? 156 : 152;
    const int CWv      = owned + 96;
    const int exBase   = owned >> 2;            // 38 or 39
    const float* ebase = emisP + (size_t)wv * 100 * SPW;
    __shared__ float box[2][4][104];            // parity x wave x padded row

    // per-lane weights: W[pair][k] = (in_k(pos 4l+pair), in_k(pos 4l+pair+2))
    v2f W[2][4];
    {
        float4 wq[4];
        #pragma unroll
        for (int c = 0; c < 4; ++c) {
            int pos = 4*l + c;
            if (pos < CWv) wq[c] = wIn2[(haloBase + pos) % S];
            else           wq[c] = make_float4(0.f, 0.f, 0.f, 0.f);
        }
        W[0][0].x = wq[0].x;  W[0][0].y = wq[2].x;
        W[0][1].x = wq[0].y;  W[0][1].y = wq[2].y;
        W[0][2].x = wq[0].z;  W[0][2].y = wq[2].z;
        W[0][3].x = wq[0].w;  W[0][3].y = wq[2].w;
        W[1][0].x = wq[1].x;  W[1][0].y = wq[3].x;
        W[1][1].x = wq[1].y;  W[1][1].y = wq[3].y;
        W[1][2].x = wq[1].z;  W[1][2].y = wq[3].z;
        W[1][3].x = wq[1].w;  W[1][3].y = wq[3].w;
    }
    const float zmask = (l >= 24 && l < 24 + (owned >> 2)) ? 1.0f : 0.0f;

    // obs blocks (uniform scalar regs): a* = obs[32g..32g+31], b* = next 32
    int4 a0, a1, a2, a3, a4, a5, a6, a7, b0, b1, b2, b3, b4, b5, b6, b7;
    {
        const int4* o4 = (const int4*)obp;
        a0 = o4[0];  a1 = o4[1];  a2 = o4[2];  a3 = o4[3];
        a4 = o4[4];  a5 = o4[5];  a6 = o4[6];  a7 = o4[7];
        b0 = o4[8];  b1 = o4[9];  b2 = o4[10]; b3 = o4[11];
        b4 = o4[12]; b5 = o4[13]; b6 = o4[14]; b7 = o4[15];
    }

    v2f p[2];
    p[0] = (v2f){0.f,0.f}; p[1] = (v2f){0.f,0.f};
    float ll = 0.0f;
    float zl = 0.0f;
    v2f eb[4][2];
    int par = 0;

    // t = 0: states 0..3 live at wave0 local pos 96..99 (lane 24)
    {
        int o0 = __builtin_amdgcn_readfirstlane(a0.x);
        float4 q = *(const float4*)(ebase + o0*SPW + 4*l);
        if (wv == 0 && l == 24) {
            p[0].x = q.x * Ivec[0];   // state 0 (pos 96)
            p[0].y = q.y * Ivec[2];   // state 2 (pos 98)
            p[1].x = q.z * Ivec[1];   // state 1 (pos 97)
            p[1].y = q.w * Ivec[3];   // state 3 (pos 99)
        }
    }

    // initial emission buffers for steps 1..4 (ids 1,2,3,0) — BEFORE boundary
    // so the boundary's inv-fold into eb[1] applies to step 1.
    PFX(1, a0.y); PFX(2, a0.z); PFX(3, a0.w); PFX(0, a1.x);

    // t=0 z: inline reduce (once), then boundary
    SNAP();
    ZST(0x111); ZST(0x112); ZST(0x114); ZST(0x118); ZST(0x142); ZST(0x143);
    BOUNDARY();

    // windows g = 0..254: steps 32g+1 .. 32g+32, boundary after each.
    // Refill at step t targets t+4; z snapshot after step 26, spread 27..32.
    #pragma unroll 1
    for (int g = 0; g < 255; ++g) {
        STEPX(1, a1.y); STEPX(2, a1.z); STEPX(3, a1.w); STEPX(0, a2.x);
        STEPX(1, a2.y); STEPX(2, a2.z); STEPX(3, a2.w); STEPX(0, a3.x);
        STEPX(1, a3.y); STEPX(2, a3.z); STEPX(3, a3.w); STEPX(0, a4.x);
        STEPX(1, a4.y); STEPX(2, a4.z); STEPX(3, a4.w); STEPX(0, a5.x);
        STEPX(1, a5.y); STEPX(2, a5.z); STEPX(3, a5.w); STEPX(0, a6.x);
        STEPX(1, a6.y); STEPX(2, a6.z);
        SNAP();
        STEPX(3, a6.w); ZST(0x111);
        STEPX(0, a7.x); ZST(0x112);
        STEPX(1, a7.y); ZST(0x114);
        STEPX(2, a7.z); ZST(0x118);
        STEPX(3, a7.w); ZST(0x142);
        STEPX(0, b0.x); ZST(0x143);
        STEPX(1, b0.y); STEPX(2, b0.z); STEPX(3, b0.w); STEPX(0, b1.x);
        BOUNDARY();
        a1 = b1; a2 = b2; a3 = b3; a4 = b4; a5 = b5; a6 = b6; a7 = b7;
        int off = 32*(g+2); if (off > TT-32) off = TT-32;
        const int4* o4 = (const int4*)(obp + off);
        b0 = o4[0]; b1 = o4[1]; b2 = o4[2]; b3 = o4[3];
        b4 = o4[4]; b5 = o4[5]; b6 = o4[6]; b7 = o4[7];
    }

    // final partial window: steps 8161..8191 (31 steps; 27 refill + 4 consume)
    STEPX(1, a1.y); STEPX(2, a1.z); STEPX(3, a1.w); STEPX(0, a2.x);
    STEPX(1, a2.y); STEPX(2, a2.z); STEPX(3, a2.w); STEPX(0, a3.x);
    STEPX(1, a3.y); STEPX(2, a3.z); STEPX(3, a3.w); STEPX(0, a4.x);
    STEPX(1, a4.y); STEPX(2, a4.z); STEPX(3, a4.w); STEPX(0, a5.x);
    STEPX(1, a5.y); STEPX(2, a5.z); STEPX(3, a5.w); STEPX(0, a6.x);
    STEPX(1, a6.y); STEPX(2, a6.z); STEPX(3, a6.w); STEPX(0, a7.x);
    STEPX(1, a7.y); STEPX(2, a7.z); STEPX(3, a7.w);
    STEPC(0); STEPC(1); STEPC(2); STEPC(3);

    // final z (cross-wave)
    {
        v2f t = p[0] + p[1];
        float zr = (t.x + t.y) * zmask;
        zr = dpp_add<0x111>(zr); zr = dpp_add<0x112>(zr);
        zr = dpp_add<0x114>(zr); zr = dpp_add<0x118>(zr);
        zr = dpp_add<0x142>(zr); zr = dpp_add<0x143>(zr);
        if (l == 63) box[par][wv][96] = zr;
        __syncthreads();
        float z = ((box[par][0][96] + box[par][1][96]) +
                   (box[par][2][96] + box[par][3][96]));
        ll += __logf(z);
    }
    if (tid == 0) out[b] = ll;
}

extern "C" void kernel_launch(void* const* d_in, const int* in_sizes, int n_in,
                              void* d_out, int out_size, void* d_ws, size_t ws_size,
                              hipStream_t stream)
{
    const float* x  = (const float*)d_in[0];   // inputs [32,8192,101]
    const float* ik = (const float*)d_in[1];   // init_kernel [4]
    const float* tk = (const float*)d_in[2];   // transition_kernel [1836]
    const float* ek = (const float*)d_in[3];   // emission_kernel [58656]
    float* out = (float*)d_out;

    char* ws = (char*)d_ws;
    float*  wIn2  = (float*)(ws + WIN_OFF);
    float*  Ivec  = (float*)(ws + IV_OFF);
    float*  emisP = (float*)(ws + EMIS_OFF);
    int*    obs   = (int*)(ws + OBS_OFF);

    hipLaunchKernelGGL(prep_tables, dim3(3), dim3(256), 0, stream, tk, ik, wIn2, Ivec);
    hipLaunchKernelGGL(prep_emis4, dim3((4*100*SPW + 255)/256), dim3(256), 0, stream,
                       ek, emisP);
    hipLaunchKernelGGL(extract_obs, dim3((NB*TT + 3)/4), dim3(256), 0, stream, x, obs);
    hipLaunchKernelGGL(forward, dim3(NB), dim3(256), 0, stream,
                       emisP, (const float4*)wIn2, Ivec, obs, out);
}

// Round 21
// 519.135 us; speedup vs baseline: 1.0595x; 1.0595x over previous
//
#include <hip/hip_runtime.h>
#include <math.h>

#pragma clang fp contract(fast)

#define S    612
#define TT   8192
#define NB   32
#define SPW  256          // per-wave emission row width in floats (4 per lane)

typedef float v2f __attribute__((ext_vector_type(2)));

// workspace layout (bytes)
#define WIN_OFF   0        // 640 float4 = 10240
#define IV_OFF    10240    // 4 floats
#define EMIS_OFF  16384    // 4*100*256 floats = 409600 -> ends 425984
#define OBS_OFF   425984   // 32*8192 ints = 1 MB

// incoming-weight table: wIn2[t] = (in0,in1,in2,in3), in_k = row((t-k)%S)[k]
__global__ __launch_bounds__(256) void prep_tables(
    const float* __restrict__ tk, const float* __restrict__ ik,
    float* __restrict__ wIn2, float* __restrict__ Ivec)
{
    int i = blockIdx.x * 256 + threadIdx.x;
    if (i < S) {
        float l0 = tk[3*i], l1 = tk[3*i+1], l2 = tk[3*i+2], l3 = 1.0f;
        float m = fmaxf(fmaxf(l0, l1), fmaxf(l2, l3));
        float e0 = expf(l0-m), e1 = expf(l1-m), e2 = expf(l2-m), e3 = expf(l3-m);
        float inv = 1.0f / (e0+e1+e2+e3);
        wIn2[4*i + 0]              = e0*inv;
        wIn2[4*((i+1)%S) + 1]      = e1*inv;
        wIn2[4*((i+2)%S) + 2]      = e2*inv;
        wIn2[4*((i+3)%S) + 3]      = e3*inv;
    } else if (i < 640) {
        wIn2[4*i+0] = 0.f; wIn2[4*i+1] = 0.f; wIn2[4*i+2] = 0.f; wIn2[4*i+3] = 0.f;
    } else if (i == 640) {
        float l0 = ik[0], l1 = ik[1], l2 = ik[2], l3 = ik[3];
        float m = fmaxf(fmaxf(l0,l1), fmaxf(l2,l3));
        float e0 = expf(l0-m), e1 = expf(l1-m), e2 = expf(l2-m), e3 = expf(l3-m);
        float inv = 1.0f / (e0+e1+e2+e3);
        Ivec[0]=e0*inv; Ivec[1]=e1*inv; Ivec[2]=e2*inv; Ivec[3]=e3*inv;
    }
}

// per-wave emission tables; wave wv, row o, lane ln holds float4
// (E(pos0),E(pos2),E(pos1),E(pos3)) for local pos 4*ln+c,
// state s = (haloBase_wv + pos) % 612; zero for pads / state 611.
// halo = 96 positions; owned = 152 (wv 0..2) / 156 (wv 3).
__global__ __launch_bounds__(256) void prep_emis4(
    const float* __restrict__ ek, float* __restrict__ emisP)
{
    int tid = blockIdx.x * 256 + threadIdx.x;
    if (tid >= 4*100*SPW) return;
    int wv = tid / (100*SPW);
    int r  = tid % (100*SPW);
    int o  = r / SPW;
    int q  = r % SPW;
    int ln = q >> 2, j = q & 3;
    int c = (j==0) ? 0 : (j==1) ? 2 : (j==2) ? 1 : 3;
    int pos = 4*ln + c;
    int haloBase = (wv==0) ? 516 : (wv==1) ? 56 : (wv==2) ? 208 : 360;
    int CWv = (wv==3) ? 252 : 248;
    float val = 0.0f;
    if (pos < CWv) {
        int s = (haloBase + pos) % S;
        if (s < S-1) {
            int ctx = o >> 2, le = o & 3;
            if (ctx == 0) {
                val = 0.25f;
            } else {
                const float* g = ek + s*96 + (ctx-1)*4;
                float a0=g[0], a1=g[1], a2=g[2], a3=g[3];
                float m = fmaxf(fmaxf(a0,a1), fmaxf(a2,a3));
                float x0=expf(a0-m), x1=expf(a1-m), x2=expf(a2-m), x3=expf(a3-m);
                float inv = 1.0f/(x0+x1+x2+x3);
                val = ((le==0)?x0:(le==1)?x1:(le==2)?x2:x3) * inv;
            }
        }
    }
    emisP[tid] = val;
}

__global__ __launch_bounds__(256) void extract_obs(
    const float* __restrict__ x, int* __restrict__ obs)
{
    int row  = blockIdx.x * 4 + (threadIdx.x >> 6);
    int lane = threadIdx.x & 63;
    if (row >= NB*TT) return;
    const float* r = x + (size_t)row * 101;
    float acc = r[lane] * (float)lane;
    if (lane < 37) acc += r[64 + lane] * (float)(64 + lane);
    #pragma unroll
    for (int m = 32; m >= 1; m >>= 1) acc += __shfl_xor(acc, m, 64);
    if (lane == 0) obs[row] = (int)(acc + 0.5f);
}

__device__ __forceinline__ float dpp_up1(float x) {
    int xi = __builtin_bit_cast(int, x);
    int r = __builtin_amdgcn_update_dpp(0, xi, 0x138, 0xF, 0xF, true);
    return __builtin_bit_cast(float, r);
}
template<int CTRL>
__device__ __forceinline__ float dpp_add(float x) {
    int sh = __builtin_amdgcn_update_dpp(0, __builtin_bit_cast(int, x), CTRL, 0xF, 0xF, true);
    return x + __builtin_bit_cast(float, sh);
}

// 2-pair core (R19 chained form): p[0]=(pos0,pos2), p[1]=(pos1,pos3).
// Lane 0's missing predecessors are DPP zeros -> garbage creeps into the
// 96-halo only (3 positions/step, 32 steps); no wrap patch needed.
#define CORE(E0,E1)                                                          \
  {                                                                          \
    float pm1 = dpp_up1(p[1].y);        /* pos 4l-1 */                       \
    float pm2 = dpp_up1(p[0].y);        /* pos 4l-2 */                       \
    float pm3 = dpp_up1(p[1].x);        /* pos 4l-3 */                       \
    v2f B1; B1.x = pm1; B1.y = p[1].x;                                       \
    v2f B2; B2.x = pm2; B2.y = p[0].x;                                       \
    v2f B3; B3.x = pm3; B3.y = pm1;                                          \
    v2f c0 = p[0]*W[0][0] + B1*W[0][1]   + B2*W[0][2] + B3*W[0][3];          \
    v2f c1 = p[1]*W[1][0] + p[0]*W[1][1] + B1*W[1][2] + B2*W[1][3];          \
    p[0] = c0*(E0); p[1] = c1*(E1);                                          \
  }

#define PFX(JB, OV)                                                          \
  { int _oo = __builtin_amdgcn_readfirstlane(OV);                            \
    float4 _q = *(const float4*)(ebase + _oo*SPW + 4*l);                     \
    eb[JB][0] = (v2f){_q.x,_q.y};                                            \
    eb[JB][1] = (v2f){_q.z,_q.w}; }

#define STEPX(JB, OV)  CORE(eb[JB][0],eb[JB][1]); PFX(JB, OV);
#define STEPC(JB)      CORE(eb[JB][0],eb[JB][1]);

// spread z-reduce: snapshot masked sum, then one DPP stage per step
#define SNAP()  { v2f _t = p[0] + p[1]; zl = (_t.x + _t.y) * zmask; }
#define ZST(C)  zl = dpp_add<C>(zl);

// boundary: zl already fully reduced (spread over steps 27..32).
// Halo+z exchange via LDS, then fold 1/z into the NEXT step's emission
// buffer (eb[1]) instead of scaling p on-chain; logf off-chain into ll.
#define BOUNDARY()                                                           \
  { if (l >= exBase && l < exBase + 24) {                                    \
      float* _o = &box[par][wv][4*(l - exBase)];                             \
      _o[0]=p[0].x; _o[1]=p[1].x; _o[2]=p[0].y; _o[3]=p[1].y;                \
    }                                                                        \
    if (l == 63) box[par][wv][96] = zl;                                      \
    __syncthreads();                                                         \
    if (l < 24) {                                                            \
      const float* _q = &box[par][(wv+3)&3][4*l];                            \
      p[0].x=_q[0]; p[1].x=_q[1]; p[0].y=_q[2]; p[1].y=_q[3];                \
    }                                                                        \
    float z = ((box[par][0][96] + box[par][1][96]) +                         \
               (box[par][2][96] + box[par][3][96]));                         \
    float inv_ = __builtin_amdgcn_rcpf(z);                                   \
    ll += __logf(z);                                                         \
    v2f _iv; _iv.x = inv_; _iv.y = inv_;                                     \
    eb[1][0] = eb[1][0]*_iv; eb[1][1] = eb[1][1]*_iv;                        \
    par ^= 1; }

// 4 waves per block, 1 batch per block; wave wv owns 152/156 states + 96 halo;
// 32-step windows between boundaries.
__global__ __launch_bounds__(256, 1) void forward(
    const float* __restrict__ emisP, const float4* __restrict__ wIn2,
    const float* __restrict__ Ivec, const int* __restrict__ obs,
    float* __restrict__ out)
{
    const int tid = threadIdx.x;
    const int l   = tid & 63;
    const int wv  = tid >> 6;
    const int b   = blockIdx.x;
    const int* obp = obs + b * TT;
    const int haloBase = (wv==0) ? 516 : (wv==1) ? 56 : (wv==2) ? 208 : 360;
    const int owned    = (wv==3) ? 156 : 152;
    const int CWv      = owned + 96;
    const int exBase   = owned >> 2;            // 38 or 39
    const float* ebase = emisP + (size_t)wv * 100 * SPW;
    __shared__ float box[2][4][104];            // parity x wave x padded row

    // per-lane weights: W[pair][k] = (in_k(pos 4l+pair), in_k(pos 4l+pair+2))
    v2f W[2][4];
    {
        float4 wq[4];
        #pragma unroll
        for (int c = 0; c < 4; ++c) {
            int pos = 4*l + c;
            if (pos < CWv) wq[c] = wIn2[(haloBase + pos) % S];
            else           wq[c] = make_float4(0.f, 0.f, 0.f, 0.f);
        }
        W[0][0].x = wq[0].x;  W[0][0].y = wq[2].x;
        W[0][1].x = wq[0].y;  W[0][1].y = wq[2].y;
        W[0][2].x = wq[0].z;  W[0][2].y = wq[2].z;
        W[0][3].x = wq[0].w;  W[0][3].y = wq[2].w;
        W[1][0].x = wq[1].x;  W[1][0].y = wq[3].x;
        W[1][1].x = wq[1].y;  W[1][1].y = wq[3].y;
        W[1][2].x = wq[1].z;  W[1][2].y = wq[3].z;
        W[1][3].x = wq[1].w;  W[1][3].y = wq[3].w;
    }
    const float zmask = (l >= 24 && l < 24 + (owned >> 2)) ? 1.0f : 0.0f;

    // obs blocks (uniform scalar regs): a* = obs[32g..32g+31], b* = next 32
    int4 a0, a1, a2, a3, a4, a5, a6, a7, b0, b1, b2, b3, b4, b5, b6, b7;
    {
        const int4* o4 = (const int4*)obp;
        a0 = o4[0];  a1 = o4[1];  a2 = o4[2];  a3 = o4[3];
        a4 = o4[4];  a5 = o4[5];  a6 = o4[6];  a7 = o4[7];
        b0 = o4[8];  b1 = o4[9];  b2 = o4[10]; b3 = o4[11];
        b4 = o4[12]; b5 = o4[13]; b6 = o4[14]; b7 = o4[15];
    }

    v2f p[2];
    p[0] = (v2f){0.f,0.f}; p[1] = (v2f){0.f,0.f};
    float ll = 0.0f;
    float zl = 0.0f;
    v2f eb[4][2];
    int par = 0;

    // t = 0: states 0..3 live at wave0 local pos 96..99 (lane 24)
    {
        int o0 = __builtin_amdgcn_readfirstlane(a0.x);
        float4 q = *(const float4*)(ebase + o0*SPW + 4*l);
        if (wv == 0 && l == 24) {
            p[0].x = q.x * Ivec[0];   // state 0 (pos 96)
            p[0].y = q.y * Ivec[2];   // state 2 (pos 98)
            p[1].x = q.z * Ivec[1];   // state 1 (pos 97)
            p[1].y = q.w * Ivec[3];   // state 3 (pos 99)
        }
    }

    // initial emission buffers for steps 1..4 (ids 1,2,3,0) — BEFORE boundary
    // so the boundary's inv-fold into eb[1] applies to step 1.
    PFX(1, a0.y); PFX(2, a0.z); PFX(3, a0.w); PFX(0, a1.x);

    // t=0 z: inline reduce (once), then boundary
    SNAP();
    ZST(0x111); ZST(0x112); ZST(0x114); ZST(0x118); ZST(0x142); ZST(0x143);
    BOUNDARY();

    // windows g = 0..254: steps 32g+1 .. 32g+32, boundary after each.
    // Refill at step t targets t+4; z snapshot after step 26, spread 27..32.
    #pragma unroll 1
    for (int g = 0; g < 255; ++g) {
        STEPX(1, a1.y); STEPX(2, a1.z); STEPX(3, a1.w); STEPX(0, a2.x);
        STEPX(1, a2.y); STEPX(2, a2.z); STEPX(3, a2.w); STEPX(0, a3.x);
        STEPX(1, a3.y); STEPX(2, a3.z); STEPX(3, a3.w); STEPX(0, a4.x);
        STEPX(1, a4.y); STEPX(2, a4.z); STEPX(3, a4.w); STEPX(0, a5.x);
        STEPX(1, a5.y); STEPX(2, a5.z); STEPX(3, a5.w); STEPX(0, a6.x);
        STEPX(1, a6.y); STEPX(2, a6.z);
        SNAP();
        STEPX(3, a6.w); ZST(0x111);
        STEPX(0, a7.x); ZST(0x112);
        STEPX(1, a7.y); ZST(0x114);
        STEPX(2, a7.z); ZST(0x118);
        STEPX(3, a7.w); ZST(0x142);
        STEPX(0, b0.x); ZST(0x143);
        STEPX(1, b0.y); STEPX(2, b0.z); STEPX(3, b0.w); STEPX(0, b1.x);
        BOUNDARY();
        a1 = b1; a2 = b2; a3 = b3; a4 = b4; a5 = b5; a6 = b6; a7 = b7;
        int off = 32*(g+2); if (off > TT-32) off = TT-32;
        const int4* o4 = (const int4*)(obp + off);
        b0 = o4[0]; b1 = o4[1]; b2 = o4[2]; b3 = o4[3];
        b4 = o4[4]; b5 = o4[5]; b6 = o4[6]; b7 = o4[7];
    }

    // final partial window: steps 8161..8191 (31 steps; 27 refill + 4 consume)
    STEPX(1, a1.y); STEPX(2, a1.z); STEPX(3, a1.w); STEPX(0, a2.x);
    STEPX(1, a2.y); STEPX(2, a2.z); STEPX(3, a2.w); STEPX(0, a3.x);
    STEPX(1, a3.y); STEPX(2, a3.z); STEPX(3, a3.w); STEPX(0, a4.x);
    STEPX(1, a4.y); STEPX(2, a4.z); STEPX(3, a4.w); STEPX(0, a5.x);
    STEPX(1, a5.y); STEPX(2, a5.z); STEPX(3, a5.w); STEPX(0, a6.x);
    STEPX(1, a6.y); STEPX(2, a6.z); STEPX(3, a6.w); STEPX(0, a7.x);
    STEPX(1, a7.y); STEPX(2, a7.z); STEPX(3, a7.w);
    STEPC(0); STEPC(1); STEPC(2); STEPC(3);

    // final z (cross-wave)
    {
        v2f t = p[0] + p[1];
        float zr = (t.x + t.y) * zmask;
        zr = dpp_add<0x111>(zr); zr = dpp_add<0x112>(zr);
        zr = dpp_add<0x114>(zr); zr = dpp_add<0x118>(zr);
        zr = dpp_add<0x142>(zr); zr = dpp_add<0x143>(zr);
        if (l == 63) box[par][wv][96] = zr;
        __syncthreads();
        float z = ((box[par][0][96] + box[par][1][96]) +
                   (box[par][2][96] + box[par][3][96]));
        ll += __logf(z);
    }
    if (tid == 0) out[b] = ll;
}

extern "C" void kernel_launch(void* const* d_in, const int* in_sizes, int n_in,
                              void* d_out, int out_size, void* d_ws, size_t ws_size,
                              hipStream_t stream)
{
    const float* x  = (const float*)d_in[0];   // inputs [32,8192,101]
    const float* ik = (const float*)d_in[1];   // init_kernel [4]
    const float* tk = (const float*)d_in[2];   // transition_kernel [1836]
    const float* ek = (const float*)d_in[3];   // emission_kernel [58656]
    float* out = (float*)d_out;

    char* ws = (char*)d_ws;
    float*  wIn2  = (float*)(ws + WIN_OFF);
    float*  Ivec  = (float*)(ws + IV_OFF);
    float*  emisP = (float*)(ws + EMIS_OFF);
    int*    obs   = (int*)(ws + OBS_OFF);

    hipLaunchKernelGGL(prep_tables, dim3(3), dim3(256), 0, stream, tk, ik, wIn2, Ivec);
    hipLaunchKernelGGL(prep_emis4, dim3((4*100*SPW + 255)/256), dim3(256), 0, stream,
                       ek, emisP);
    hipLaunchKernelGGL(extract_obs, dim3((NB*TT + 3)/4), dim3(256), 0, stream, x, obs);
    hipLaunchKernelGGL(forward, dim3(NB), dim3(256), 0, stream,
                       emisP, (const float4*)wIn2, Ivec, obs, out);
}